// Round 5
// baseline (333.155 us; speedup 1.0000x reference)
//
#include <hip/hip_runtime.h>

// fg/bg masked unbiased variance, Pred/GT fp32 [4096,1,100,100].
// One-pass var: var = (sumsq - n*mean^2)/(n-1)  (exact rewrite of reference).
// Round 5 change: WAVE-per-sample (was block-per-sample). 1024 blocks x 4
// waves, each wave owns one sample end-to-end: no LDS, no __syncthreads,
// no serial epilogue, zero block-generation turnover (all waves resident
// for the whole kernel), continuous double-buffered load stream
// (3-round groups, 6 loads in flight/wave). Probes the "short-lived block
// turnover" theory for the 118us plateau (latency model says ~55us).

#define NSAMP   4096
#define ELEMS   10000          // 100*100 per sample
#define VECS    (ELEMS / 4)    // 2500 float4 per sample
#define BLOCK   256
#define WPB     4              // waves per block
#define NBLK    (NSAMP / WPB)  // 1024
#define RPG     3              // rounds (of 64 lanes) per group
#define GROUPS  13             // 13*3*64 = 2496 vec4s
#define TAILV   (VECS - GROUPS * RPG * 64)  // 4 (lanes 0..3)

__device__ __forceinline__ void consume(float4 p, float4 g,
        float& cfg, float& sfg, float& qfg,
        float& cbg, float& sbg, float& qbg) {
    #pragma unroll
    for (int c = 0; c < 4; ++c) {
        float pp = (&p.x)[c];
        float gg = (&g.x)[c];
        float sq = pp * pp;
        bool  nz = (pp != 0.0f);
        float fg = (gg > 0.5f && nz) ? 1.0f : 0.0f;
        float bg = (gg < 0.5f && nz) ? 1.0f : 0.0f;
        cfg += fg;  sfg += fg * pp;  qfg += fg * sq;
        cbg += bg;  sbg += bg * pp;  qbg += bg * sq;
    }
}

__global__ __launch_bounds__(BLOCK) void stage1_wave_per_sample(
        const float* __restrict__ Pred,
        const float* __restrict__ GT,
        float* __restrict__ vars /* [2][NSAMP]: fg then bg */) {
    const int tid  = threadIdx.x;
    const int lane = tid & 63;
    const int wid  = tid >> 6;
    const int s    = blockIdx.x * WPB + wid;   // sample owned by this wave

    const float4* __restrict__ p4 = (const float4*)(Pred + (size_t)s * ELEMS);
    const float4* __restrict__ g4 = (const float4*)(GT   + (size_t)s * ELEMS);

    float cfg = 0.f, sfg = 0.f, qfg = 0.f;
    float cbg = 0.f, sbg = 0.f, qbg = 0.f;

    // Double-buffered groups of RPG rounds; all indices compile-time after
    // full unroll (rule #20: no runtime-indexed reg arrays reach codegen).
    float4 bp[2][RPG], bg_[2][RPG];

    #pragma unroll
    for (int r = 0; r < RPG; ++r) {
        bp [0][r] = p4[r * 64 + lane];
        bg_[0][r] = g4[r * 64 + lane];
    }

    #pragma unroll
    for (int g = 0; g < GROUPS; ++g) {
        const int cur = g & 1, nxt = cur ^ 1;
        if (g + 1 < GROUPS) {
            #pragma unroll
            for (int r = 0; r < RPG; ++r) {
                const int rr = (g + 1) * RPG + r;
                bp [nxt][r] = p4[rr * 64 + lane];
                bg_[nxt][r] = g4[rr * 64 + lane];
            }
        }
        #pragma unroll
        for (int r = 0; r < RPG; ++r)
            consume(bp[cur][r], bg_[cur][r], cfg, sfg, qfg, cbg, sbg, qbg);
    }

    if (lane < TAILV) {
        float4 p = p4[GROUPS * RPG * 64 + lane];
        float4 g = g4[GROUPS * RPG * 64 + lane];
        consume(p, g, cfg, sfg, qfg, cbg, sbg, qbg);
    }

    // ---- wave-only reduction (no LDS, no barrier) ----
    float vals[6] = {cfg, sfg, qfg, cbg, sbg, qbg};
    #pragma unroll
    for (int k = 0; k < 6; ++k) {
        float v = vals[k];
        #pragma unroll
        for (int off = 32; off > 0; off >>= 1)
            v += __shfl_down(v, off, 64);
        vals[k] = v;
    }

    if (lane == 0) {
        {
            float n    = vals[0];
            float mean = vals[1] / n;
            vars[s] = (vals[2] - n * mean * mean) / (n - 1.0f);
        }
        {
            float n    = vals[3];
            float mean = vals[4] / n;
            vars[NSAMP + s] = (vals[5] - n * mean * mean) / (n - 1.0f);
        }
    }
}

__global__ __launch_bounds__(BLOCK) void stage2_mean(
        const float* __restrict__ vars,
        float* __restrict__ out) {
    const int tid = threadIdx.x;
    float sf = 0.f, sb = 0.f;
    for (int i = tid; i < NSAMP; i += BLOCK) {
        sf += vars[i];
        sb += vars[NSAMP + i];
    }
    const int lane = tid & 63;
    const int wid  = tid >> 6;
    __shared__ float red[2][BLOCK / 64];
    float rf = sf, rb = sb;
    #pragma unroll
    for (int off = 32; off > 0; off >>= 1) {
        rf += __shfl_down(rf, off, 64);
        rb += __shfl_down(rb, off, 64);
    }
    if (lane == 0) { red[0][wid] = rf; red[1][wid] = rb; }
    __syncthreads();
    if (tid == 0) {
        float a = 0.f, b2 = 0.f;
        #pragma unroll
        for (int w = 0; w < BLOCK / 64; ++w) { a += red[0][w]; b2 += red[1][w]; }
        out[0] = a  / (float)NSAMP;  // fg_var
        out[1] = b2 / (float)NSAMP;  // bg_var
    }
}

extern "C" void kernel_launch(void* const* d_in, const int* in_sizes, int n_in,
                              void* d_out, int out_size, void* d_ws, size_t ws_size,
                              hipStream_t stream) {
    const float* Pred = (const float*)d_in[0];
    const float* GT   = (const float*)d_in[1];
    float* out  = (float*)d_out;
    float* vars = (float*)d_ws;   // 2*NSAMP floats = 32 KB

    stage1_wave_per_sample<<<NBLK, BLOCK, 0, stream>>>(Pred, GT, vars);
    stage2_mean<<<1, BLOCK, 0, stream>>>(vars, out);
}